// Round 1
// baseline (197.847 us; speedup 1.0000x reference)
//
#include <hip/hip_runtime.h>
#include <cfloat>

static constexpr int kBS  = 512;
static constexpr int kL   = 68;
static constexpr int kIMG = 224;
static constexpr int kR2  = 49;
static constexpr int kLL  = kL * kL;                       // 4624
static constexpr int kOutBlk = 256;
static constexpr int kNbx = (kLL + kOutBlk - 1) / kOutBlk; // 19
static constexpr int kNPart = kNbx * kBS;                  // 9728

// jnp.linspace(-3.5, 3.5, 7)[k] / 224 * 2 — replicating JAX's convex-combination
// linspace (start*(1-step)+stop*step, exact endpoint), no fp contraction.
__device__ __forceinline__ float lin_off(int k) {
  float x;
  if (k == 6) {
    x = 3.5f;
  } else {
    float step = __fdiv_rn((float)k, 6.0f);
    float a = __fmul_rn(-3.5f, __fsub_rn(1.0f, step));
    float b = __fmul_rn(3.5f, step);
    x = __fadd_rn(a, b);
  }
  return __fmul_rn(__fdiv_rn(x, 224.0f), 2.0f);
}

// One wave (64 lanes) per (b,l) region; lanes 0..48 hold the 7x7 samples.
__global__ __launch_bounds__(256) void k_median(
    const float* __restrict__ depth, const float* __restrict__ lmk,
    const float* __restrict__ scale, const float* __restrict__ bbox,
    float* __restrict__ med) {
  int wave = blockIdx.x * 4 + (threadIdx.x >> 6);
  int lane = threadIdx.x & 63;
  if (wave >= kBS * kL) return;
  int b = wave / kL;

  float lmx = lmk[wave * 2 + 0];
  float lmy = lmk[wave * 2 + 1];
  float sx = scale[b * 2 + 0], sy = scale[b * 2 + 1];
  float bx = bbox[b * 4 + 0],  by = bbox[b * 4 + 1];

  // face_lm = (lm - bbox)*scale/224*2 - 1, exact op order, no contraction
  float tx = __fsub_rn(lmx, bx);
  tx = __fmul_rn(tx, sx);
  tx = __fdiv_rn(tx, 224.0f);
  tx = __fmul_rn(tx, 2.0f);
  float flmx = __fsub_rn(tx, 1.0f);
  float ty = __fsub_rn(lmy, by);
  ty = __fmul_rn(ty, sy);
  ty = __fdiv_rn(ty, 224.0f);
  ty = __fmul_rn(ty, 2.0f);
  float flmy = __fsub_rn(ty, 1.0f);

  float v = FLT_MAX;  // inactive lanes sort to the top; never selected
  if (lane < kR2) {
    int i = lane / 7, j = lane - i * 7;
    float gx = __fadd_rn(flmx, lin_off(j));
    float gy = __fadd_rn(flmy, lin_off(i));
    // ix = ((gx+1)*224 - 1)*0.5 ; round half-to-even (jnp.round)
    float ix = __fmul_rn(__fsub_rn(__fmul_rn(__fadd_rn(gx, 1.0f), 224.0f), 1.0f), 0.5f);
    float iy = __fmul_rn(__fsub_rn(__fmul_rn(__fadd_rn(gy, 1.0f), 224.0f), 1.0f), 0.5f);
    int xi = (int)rintf(ix);
    int yi = (int)rintf(iy);
    bool valid = (xi >= 0) && (xi < kIMG) && (yi >= 0) && (yi < kIMG);
    int xc = min(max(xi, 0), kIMG - 1);
    int yc = min(max(yi, 0), kIMG - 1);
    float dv = depth[(size_t)b * (kIMG * kIMG) + yc * kIMG + xc];
    v = valid ? dv : 0.0f;
  }

  // rank (stable) + count of values <= THR across the 49 samples
  int cnt = 0, rank = 0;
  for (int j = 0; j < kR2; ++j) {
    float vj = __shfl(v, j, 64);
    cnt += (vj <= 1e-4f) ? 1 : 0;
    rank += ((vj < v) || (vj == v && j < lane)) ? 1 : 0;
  }
  // st = first sorted idx >= 1 with s[st] > THR; fallback 48
  int st = min(max(cnt, 1), kR2 - 1);
  int k = (st + kR2 - 1) >> 1;  // med_ind
  unsigned long long sel = __ballot(lane < kR2 && rank == k);
  int src = __ffsll(sel) - 1;
  float m = __shfl(v, src, 64);
  if (lane == 0) med[wave] = m;
}

// One block per batch: lower-median of 68 medians, mask, scale by 500.
__global__ __launch_bounds__(128) void k_mask(
    const float* __restrict__ med, float* __restrict__ m500,
    float* __restrict__ fm) {
  __shared__ float s[kL];
  __shared__ float mom_s;
  int b = blockIdx.x;
  int t = threadIdx.x;
  if (t < kL) s[t] = med[b * kL + t];
  __syncthreads();
  if (t < kL) {
    float v = s[t];
    int rank = 0;
    for (int j = 0; j < kL; ++j) {
      float vj = s[j];
      rank += ((vj < v) || (vj == v && j < t)) ? 1 : 0;
    }
    if (rank == (kL - 1) / 2) mom_s = v;  // exactly one thread
  }
  __syncthreads();
  if (t < kL) {
    float v = s[t];
    float diff = fabsf(__fsub_rn(v, mom_s));
    fm[b * kL + t] = (diff < 0.18f) ? 1.0f : 0.0f;
    m500[b * kL + t] = __fmul_rn(v, 500.0f);
  }
}

// [512,68,68]: write median_diff + mask, accumulate masked smooth-L1 partials.
__global__ __launch_bounds__(256) void k_out(
    const float* __restrict__ rdp, const float* __restrict__ m500,
    const float* __restrict__ fm, float* __restrict__ out_diff,
    float* __restrict__ out_mask, double* __restrict__ part) {
  int b = blockIdx.y;
  int t = blockIdx.x * blockDim.x + threadIdx.x;
  double pn = 0.0, pd = 0.0;
  if (t < kLL) {
    int i = t / kL, j = t - i * kL;
    float mi = m500[b * kL + i];
    float mj = m500[b * kL + j];
    float diff = __fsub_rn(mi, mj);
    float mv = __fmul_rn(fm[b * kL + i], fm[b * kL + j]);
    size_t idx = (size_t)b * kLL + t;
    out_diff[idx] = diff;
    out_mask[idx] = mv;
    float d = __fsub_rn(rdp[idx], diff);
    float ad = fabsf(d);
    float le = (ad < 1.0f) ? __fmul_rn(__fmul_rn(0.5f, d), d)
                           : __fsub_rn(ad, 0.5f);
    pn = (double)__fmul_rn(le, mv);
    pd = (double)mv;
  }
  // wave reduce then cross-wave via LDS
  for (int off = 32; off > 0; off >>= 1) {
    pn += __shfl_down(pn, off, 64);
    pd += __shfl_down(pd, off, 64);
  }
  __shared__ double sn[4], sd[4];
  int w = threadIdx.x >> 6;
  if ((threadIdx.x & 63) == 0) { sn[w] = pn; sd[w] = pd; }
  __syncthreads();
  if (threadIdx.x == 0) {
    double tn = sn[0] + sn[1] + sn[2] + sn[3];
    double td = sd[0] + sd[1] + sd[2] + sd[3];
    int pb = blockIdx.y * gridDim.x + blockIdx.x;
    part[2 * pb + 0] = tn;
    part[2 * pb + 1] = td;
  }
}

__global__ __launch_bounds__(256) void k_final(
    const double* __restrict__ part, float* __restrict__ out0) {
  double pn = 0.0, pd = 0.0;
  for (int i = threadIdx.x; i < kNPart; i += 256) {
    pn += part[2 * i + 0];
    pd += part[2 * i + 1];
  }
  for (int off = 32; off > 0; off >>= 1) {
    pn += __shfl_down(pn, off, 64);
    pd += __shfl_down(pd, off, 64);
  }
  __shared__ double sn[4], sd[4];
  int w = threadIdx.x >> 6;
  if ((threadIdx.x & 63) == 0) { sn[w] = pn; sd[w] = pd; }
  __syncthreads();
  if (threadIdx.x == 0) {
    double tn = sn[0] + sn[1] + sn[2] + sn[3];
    double td = sd[0] + sd[1] + sd[2] + sd[3];
    out0[0] = (float)(tn / (td + 1e-4));
  }
}

extern "C" void kernel_launch(void* const* d_in, const int* in_sizes, int n_in,
                              void* d_out, int out_size, void* d_ws, size_t ws_size,
                              hipStream_t stream) {
  const float* rdp   = (const float*)d_in[0];  // [512,68,68]
  const float* depth = (const float*)d_in[1];  // [512,1,224,224]
  const float* lmk   = (const float*)d_in[2];  // [512,68,2]
  const float* scale = (const float*)d_in[3];  // [512,2]
  const float* bbox  = (const float*)d_in[4];  // [512,4]

  float* out = (float*)d_out;          // [0]=loss, then diff, then mask
  float* out_diff = out + 1;
  float* out_mask = out + 1 + (size_t)kBS * kLL;

  char* ws = (char*)d_ws;
  const size_t medBytes = (size_t)kBS * kL * sizeof(float);  // 139264
  float*  med   = (float*)(ws);
  float*  m500  = (float*)(ws + medBytes);
  float*  fm    = (float*)(ws + 2 * medBytes);
  double* part  = (double*)(ws + 3 * medBytes);  // 417792, 8B aligned

  int nWaves = kBS * kL;          // 34816
  int nBlk1 = (nWaves + 3) / 4;   // 8704
  k_median<<<dim3(nBlk1), dim3(256), 0, stream>>>(depth, lmk, scale, bbox, med);
  k_mask<<<dim3(kBS), dim3(128), 0, stream>>>(med, m500, fm);
  k_out<<<dim3(kNbx, kBS), dim3(kOutBlk), 0, stream>>>(rdp, m500, fm, out_diff,
                                                       out_mask, part);
  k_final<<<dim3(1), dim3(256), 0, stream>>>(part, out);
}